// Round 24
// baseline (170.944 us; speedup 1.0000x reference)
//
#include <hip/hip_runtime.h>
#include <hip/hip_bf16.h>
#include <math.h>

#define DEV __device__ __forceinline__

using bf16x8 = __attribute__((ext_vector_type(8))) short;
using f32x4  = __attribute__((ext_vector_type(4))) float;

static constexpr int Bb = 8, Nn = 1024, Dd = 512, Hh = 8, DHd = 64, FFd = 2048;
static constexpr int Mrows = Bb * Nn; // 8192

DEV short f2bf(float f) {
  union { float f; unsigned u; } v; v.f = f;
  unsigned r = v.u + 0x7fffu + ((v.u >> 16) & 1u);
  return (short)(r >> 16);
}
DEV float bf2f(short s) {
  union { unsigned u; float f; } v; v.u = ((unsigned)(unsigned short)s) << 16;
  return v.f;
}
DEV float fexp2(float x) { return __builtin_amdgcn_exp2f(x); }

DEV f32x4 mfma16(bf16x8 a, bf16x8 b, f32x4 c) {
  return __builtin_amdgcn_mfma_f32_16x16x32_bf16(a, b, c, 0, 0, 0);
}

// swizzle64 layout for all bf16 operand buffers:
// element (row r, col k, leading-dim ld) lives at
//   (r>>6)*64*ld + (k>>3)*512 + (r&63)*8 + (k&7)
DEV size_t swz(int r, int k, int ld) {
  return (size_t)(r >> 6) * 64 * ld + (size_t)(k >> 3) * 512
       + (size_t)((r & 63) * 8 + (k & 7));
}

// async global->LDS, 16B per lane. LDS dest is wave-uniform base + lane*16.
DEV void gload16(const void* g, void* l) {
  __builtin_amdgcn_global_load_lds(
      (const __attribute__((address_space(1))) void*)g,
      (__attribute__((address_space(3))) void*)l, 16, 0, 0);
}

// gelu_new(g) = g * sigmoid(2 * 0.79788456 * (g + 0.044715 g^3)), exp2 domain
DEV float gelu_fast(float g) {
  float u2l = 2.30220822f * (g + 0.044715f * g * g * g); // 2*0.79788456*log2e
  return g / (1.0f + fexp2(-u2l));
}

// 2-D per-XCD chunk swizzle (flat wg within a (gx,gy) tile grid).
DEV void xcd_tile2(int wg, int gx, int gy, int& trow, int& tcol) {
  int xcd = wg & 7, idx = wg >> 3;
  int XC = (gx >= 16) ? 2 : 1, XR = 8 / XC;
  int lcx = gx / XC, lcy = gy / XR;
  trow = (xcd / XC) * lcy + idx / lcx;
  tcol = (xcd % XC) * lcx + idx % lcx;
}

// ---------------- merged preprocess: 7 transposes + mask + LN0 --------------
struct PreArgs {
  const float* src[7]; short* dst[7];
  const int* train; const int* batch; char* allowC;
  const float* X; const float* sc; const float* bi;
  short* xn; short* xraw;
};
__global__ __launch_bounds__(256)
void k_preprocess(PreArgs a) {
  __shared__ float tile[32][33];
  int id = blockIdx.x;
  if (id < 4096) {
    int j, rem;
    if (id < 1024)      { j = id >> 8;                 rem = id & 255; }
    else if (id < 3072) { j = 4 + ((id - 1024) >> 10); rem = (id - 1024) & 1023; }
    else                { j = 6;                       rem = id - 3072; }
    int K = (j == 6) ? 2048 : 512;
    int N = (j == 4 || j == 5) ? 2048 : 512;
    const float* W = a.src[j];
    short* WT = a.dst[j];
    int gx = N >> 5;
    int nb = (rem % gx) * 32, kb = (rem / gx) * 32;
    int tx = threadIdx.x & 31, ty = threadIdx.x >> 5;
    #pragma unroll
    for (int i = ty; i < 32; i += 8)
      tile[i][tx] = W[(size_t)(kb + i) * N + nb + tx];
    __syncthreads();
    #pragma unroll
    for (int i = ty; i < 32; i += 8)
      WT[swz(nb + i, kb + tx, K)] = f2bf(tile[tx][i]);
  } else if (id < 4128) {
    int i = (id - 4096) * 256 + threadIdx.x;
    a.allowC[i] = ((a.train[i] | a.batch[i]) != 0) ? 1 : 0;
  } else {
    int w = threadIdx.x >> 6, lane = threadIdx.x & 63;
    int row = (id - 4128) * 4 + w;
    const float* x = a.X + (size_t)row * Dd + lane * 8;
    f32x4 va = *(const f32x4*)x;
    f32x4 vb = *(const f32x4*)(x + 4);
    float p = va[0] + va[1] + va[2] + va[3] + vb[0] + vb[1] + vb[2] + vb[3];
    #pragma unroll
    for (int off = 1; off < 64; off <<= 1) p += __shfl_xor(p, off);
    float mean = p * (1.0f / Dd);
    float d[8];
    #pragma unroll
    for (int j = 0; j < 4; j++) { d[j] = va[j] - mean; d[4 + j] = vb[j] - mean; }
    float q = 0.0f;
    #pragma unroll
    for (int j = 0; j < 8; j++) q += d[j] * d[j];
    #pragma unroll
    for (int off = 1; off < 64; off <<= 1) q += __shfl_xor(q, off);
    float rs = rsqrtf(q * (1.0f / Dd) + 1e-12f);
    int c0 = lane * 8;
    f32x4 s0 = *(const f32x4*)(a.sc + c0), s1 = *(const f32x4*)(a.sc + c0 + 4);
    f32x4 b0 = *(const f32x4*)(a.bi + c0), b1 = *(const f32x4*)(a.bi + c0 + 4);
    bf16x8 o;
    #pragma unroll
    for (int j = 0; j < 4; j++) {
      o[j]     = f2bf(d[j] * rs * s0[j] + b0[j]);
      o[4 + j] = f2bf(d[4 + j] * rs * s1[j] + b1[j]);
    }
    *(bf16x8*)(a.xn + swz(row, c0, Dd)) = o;
    bf16x8 rv;
    #pragma unroll
    for (int j = 0; j < 4; j++) { rv[j] = f2bf(va[j]); rv[4 + j] = f2bf(vb[j]); }
    *(bf16x8*)(a.xraw + swz(row, c0, Dd)) = rv;
  }
}

// ---------------- layernorm for LN1: reads bf16 swz Hc, one row per WAVE ----
__global__ __launch_bounds__(256)
void k_layernorm1(const short* __restrict__ Xb, const float* __restrict__ sc,
                  const float* __restrict__ bi, short* __restrict__ out) {
  int w = threadIdx.x >> 6, lane = threadIdx.x & 63;
  int row = blockIdx.x * 4 + w;
  int c0 = lane * 8;
  bf16x8 v = *(const bf16x8*)(Xb + swz(row, c0, Dd));
  float vals[8];
  #pragma unroll
  for (int j = 0; j < 8; j++) vals[j] = bf2f(v[j]);
  float p = 0.0f;
  #pragma unroll
  for (int j = 0; j < 8; j++) p += vals[j];
  #pragma unroll
  for (int off = 1; off < 64; off <<= 1) p += __shfl_xor(p, off);
  float mean = p * (1.0f / Dd);
  float d[8];
  #pragma unroll
  for (int j = 0; j < 8; j++) d[j] = vals[j] - mean;
  float q = 0.0f;
  #pragma unroll
  for (int j = 0; j < 8; j++) q += d[j] * d[j];
  #pragma unroll
  for (int off = 1; off < 64; off <<= 1) q += __shfl_xor(q, off);
  float rs = rsqrtf(q * (1.0f / Dd) + 1e-12f);
  f32x4 s0 = *(const f32x4*)(sc + c0), s1 = *(const f32x4*)(sc + c0 + 4);
  f32x4 b0 = *(const f32x4*)(bi + c0), b1 = *(const f32x4*)(bi + c0 + 4);
  bf16x8 o;
  #pragma unroll
  for (int j = 0; j < 4; j++) {
    o[j]     = f2bf(d[j] * rs * s0[j] + b0[j]);
    o[4 + j] = f2bf(d[4 + j] * rs * s1[j] + b1[j]);
  }
  *(bf16x8*)(out + swz(row, c0, Dd)) = o;
}

// ---------------- LDS-staged bf16 MFMA GEMM: C = A[M][K] @ BT[N][K]^T -------
// A/BT in swz layout. 128 x BN tile, BK k-depth, 4 waves, 2-buf stage-ahead.
// BIASM: 0 none, 1 bias[col], 2 bias[row].
// RESM:  0 none, 1 f32 row-major, 2 bf16 swz.
template<int BN, int BK, int BIASM, int RESM, bool WF, bool WB>
__global__ __launch_bounds__(256, 4)
void k_gemm128(const short* __restrict__ A, const short* __restrict__ BT,
               const float* __restrict__ bias, const float* __restrict__ resF,
               const short* __restrict__ resB,
               float* __restrict__ outF, short* __restrict__ outB,
               int M, int N, int K) {
  constexpr int FN = BN / 32;   // frag cols per wave
  __shared__ short lA[2][128 * BK];
  __shared__ short lB[2][BN * BK];
  int tid = threadIdx.x, w = tid >> 6, lane = tid & 63;
  int lr = lane & 15, lg = lane >> 4;
  int wr = w >> 1, wc = w & 1;
  int trow, tcol;
  xcd_tile2(blockIdx.y * gridDim.x + blockIdx.x, gridDim.x, gridDim.y, trow, tcol);
  int row0 = trow * 128, col0 = tcol * BN;
  f32x4 acc[4][FN] = {};

  auto stage = [&](int buf, int k0) {
    #pragma unroll
    for (int i = 0; i < BK / 16; i++) {
      int c = i * 4 + w;
      gload16(A + swz(row0 + (c & 1) * 64 + lane, k0 + (c >> 1) * 8, K),
              &lA[buf][c * 512]);
    }
    #pragma unroll
    for (int i = 0; i < (BN * BK) / 2048; i++) {
      int c = i * 4 + w;
      if (BN == 128)
        gload16(BT + swz(col0 + (c & 1) * 64 + lane, k0 + (c >> 1) * 8, K),
                &lB[buf][c * 512]);
      else
        gload16(BT + swz(col0 + lane, k0 + c * 8, K), &lB[buf][c * 512]);
    }
  };

  stage(0, 0);
  __syncthreads();
  int nt = K / BK, buf = 0;
  for (int t = 0; t < nt; t++) {
    if (t + 1 < nt) stage(buf ^ 1, (t + 1) * BK);
    #pragma unroll
    for (int kk = 0; kk < BK / 32; kk++) {
      bf16x8 af[4];
      #pragma unroll
      for (int m = 0; m < 4; m++)
        af[m] = *(const bf16x8*)&lA[buf][(kk * 4 + lg) * 1024 + (wr * 64 + m * 16 + lr) * 8];
      #pragma unroll
      for (int n = 0; n < FN; n++) {
        bf16x8 bfr = *(const bf16x8*)&lB[buf][(kk * 4 + lg) * (BN * 8)
                                              + (wc * (BN / 2) + n * 16 + lr) * 8];
        #pragma unroll
        for (int m = 0; m < 4; m++)
          acc[m][n] = mfma16(af[m], bfr, acc[m][n]);
      }
    }
    __syncthreads();
    buf ^= 1;
  }

  #pragma unroll
  for (int n = 0; n < FN; n++) {
    int col = col0 + wc * (BN / 2) + n * 16 + lr;
    float bv = (BIASM == 1) ? bias[col] : 0.0f;
    #pragma unroll
    for (int m = 0; m < 4; m++) {
      #pragma unroll
      for (int r = 0; r < 4; r++) {
        int rowg = row0 + wr * 64 + m * 16 + lg * 4 + r;
        float vv = acc[m][n][r] + bv;
        if (BIASM == 2) vv += bias[rowg];
        if (RESM == 1) vv += resF[(size_t)rowg * N + col];
        if (RESM == 2) vv += bf2f(resB[swz(rowg, col, N)]);
        if (WF) outF[(size_t)rowg * N + col] = vv;
        if (WB) outB[swz(rowg, col, N)] = f2bf(vv);
      }
    }
  }
}

// ---------------- fused GEGLU, BN=64 dual-acc: FF = gelu(x1@wi0^T)*(x1@wi1^T)
// M=8192, N=2048, K=512, BK=32. LDS 32KB, acc 64 VGPR.
// launch_bounds (256,4): do NOT tighten to (256,5) -- the ~96-VGPR cap spills
// the accumulators to scratch (R22: 46->210us, FETCH 30->270MB).
__global__ __launch_bounds__(256, 4)
void k_geglu64(const short* __restrict__ A, const short* __restrict__ BT0,
               const short* __restrict__ BT1, short* __restrict__ outB) {
  constexpr int BN = 64, BK = 32, K = 512, N = 2048;
  __shared__ short lA[2][128 * BK];
  __shared__ short lB0[2][BN * BK];
  __shared__ short lB1[2][BN * BK];
  int tid = threadIdx.x, w = tid >> 6, lane = tid & 63;
  int lr = lane & 15, lg = lane >> 4;
  int wr = w >> 1, wc = w & 1;
  int trow, tcol;
  xcd_tile2(blockIdx.x, N / BN, Mrows / 128, trow, tcol);
  int row0 = trow * 128, col0 = tcol * BN;
  f32x4 acc0[4][2] = {}, acc1[4][2] = {};

  auto stage = [&](int buf, int k0) {
    #pragma unroll
    for (int i = 0; i < 2; i++) {           // A: 8 chunks of 1KB
      int c = i * 4 + w;
      gload16(A + swz(row0 + (c & 1) * 64 + lane, k0 + (c >> 1) * 8, K),
              &lA[buf][c * 512]);
    }
    {
      int c = w;                            // B0, B1: 4 chunks each
      gload16(BT0 + swz(col0 + lane, k0 + c * 8, K), &lB0[buf][c * 512]);
      gload16(BT1 + swz(col0 + lane, k0 + c * 8, K), &lB1[buf][c * 512]);
    }
  };

  stage(0, 0);
  __syncthreads();
  int nt = K / BK, buf = 0;
  for (int t = 0; t < nt; t++) {
    if (t + 1 < nt) stage(buf ^ 1, (t + 1) * BK);
    bf16x8 af[4];
    #pragma unroll
    for (int m = 0; m < 4; m++)
      af[m] = *(const bf16x8*)&lA[buf][lg * 1024 + (wr * 64 + m * 16 + lr) * 8];
    #pragma unroll
    for (int n = 0; n < 2; n++) {
      bf16x8 b0 = *(const bf16x8*)&lB0[buf][lg * (BN * 8) + (wc * 32 + n * 16 + lr) * 8];
      #pragma unroll
      for (int m = 0; m < 4; m++)
        acc0[m][n] = mfma16(af[m], b0, acc0[m][n]);
      bf16x8 b1 = *(const bf16x8*)&lB1[buf][lg * (BN * 8) + (wc * 32 + n * 16 + lr) * 8];
      #pragma unroll
      for (int m = 0; m < 4; m++)
        acc1[m][n] = mfma16(af[m], b1, acc1[m][n]);
    }
    __syncthreads();
    buf ^= 1;
  }

  #pragma unroll
  for (int n = 0; n < 2; n++) {
    int col = col0 + wc * 32 + n * 16 + lr;
    #pragma unroll
    for (int m = 0; m < 4; m++) {
      #pragma unroll
      for (int r = 0; r < 4; r++) {
        int rowg = row0 + wr * 64 + m * 16 + lg * 4 + r;
        outB[swz(rowg, col, N)] = f2bf(gelu_fast(acc0[m][n][r]) * acc1[m][n][r]);
      }
    }
  }
}

// ---------------- merged Q/K/V^T GEMMs: one dispatch, 1536 blocks -----------
// BK=32: LDS 24KB -> 6 blocks/CU resident (grid gives 6 blocks/CU of work).
__global__ __launch_bounds__(256, 4)
void k_qkv(const short* __restrict__ Xnbf, const short* __restrict__ Xbf,
           const short* __restrict__ WqT, const short* __restrict__ WkT,
           const short* __restrict__ WvT,
           const float* __restrict__ bq, const float* __restrict__ bk,
           const float* __restrict__ bv,
           short* __restrict__ Qbf, short* __restrict__ Kbf,
           short* __restrict__ VTg) {
  constexpr int BN = 64, BK = 32, FN = 2;
  constexpr int K = 512;
  __shared__ short lA[2][128 * BK];
  __shared__ short lB[2][BN * BK];
  int id = blockIdx.x;
  int which = id >> 9, sub = id & 511;
  const short *A, *BT; const float* bias; short* outB;
  int N, gx, gy; bool rowbias;
  if (which == 0)      { A = Xnbf; BT = WqT; bias = bq; outB = Qbf; N = 512;  gx = 8;   gy = 64; rowbias = false; }
  else if (which == 1) { A = Xbf;  BT = WkT; bias = bk; outB = Kbf; N = 512;  gx = 8;   gy = 64; rowbias = false; }
  else                 { A = WvT;  BT = Xbf; bias = bv; outB = VTg; N = 8192; gx = 128; gy = 4;  rowbias = true;  }
  int tid = threadIdx.x, w = tid >> 6, lane = tid & 63;
  int lr = lane & 15, lg = lane >> 4;
  int wr = w >> 1, wc = w & 1;
  int trow, tcol;
  xcd_tile2(sub, gx, gy, trow, tcol);
  int row0 = trow * 128, col0 = tcol * BN;
  f32x4 acc[4][FN] = {};

  auto stage = [&](int buf, int k0) {
    #pragma unroll
    for (int i = 0; i < 2; i++) {          // A: 8 chunks of 1KB
      int c = i * 4 + w;
      gload16(A + swz(row0 + (c & 1) * 64 + lane, k0 + (c >> 1) * 8, K),
              &lA[buf][c * 512]);
    }
    {
      int c = w;                           // B: 4 chunks
      gload16(BT + swz(col0 + lane, k0 + c * 8, K), &lB[buf][c * 512]);
    }
  };

  stage(0, 0);
  __syncthreads();
  int nt = K / BK, buf = 0;
  for (int t = 0; t < nt; t++) {
    if (t + 1 < nt) stage(buf ^ 1, (t + 1) * BK);
    bf16x8 af[4];
    #pragma unroll
    for (int m = 0; m < 4; m++)
      af[m] = *(const bf16x8*)&lA[buf][lg * 1024 + (wr * 64 + m * 16 + lr) * 8];
    #pragma unroll
    for (int n = 0; n < FN; n++) {
      bf16x8 bfr = *(const bf16x8*)&lB[buf][lg * (BN * 8)
                                            + (wc * (BN / 2) + n * 16 + lr) * 8];
      #pragma unroll
      for (int m = 0; m < 4; m++)
        acc[m][n] = mfma16(af[m], bfr, acc[m][n]);
    }
    __syncthreads();
    buf ^= 1;
  }

  #pragma unroll
  for (int n = 0; n < FN; n++) {
    int col = col0 + wc * (BN / 2) + n * 16 + lr;
    float bvc = rowbias ? 0.0f : bias[col];
    #pragma unroll
    for (int m = 0; m < 4; m++) {
      #pragma unroll
      for (int r = 0; r < 4; r++) {
        int rowg = row0 + wr * 64 + m * 16 + lg * 4 + r;
        float vv = acc[m][n][r] + bvc;
        if (rowbias) vv += bias[rowg];
        outB[swz(rowg, col, N)] = f2bf(vv);
      }
    }
  }
}

// ---------------- flash attention, 128 q-rows/block, exp2-domain softmax ----
// Qbf/Kbf swz over [Mrows][Dd]; VT swz over [Dd][Mrows].
// grid 512; launch_bounds (256,2) -- do NOT tighten to (256,4): live state
// needs ~150 VGPR at peak, a 128 cap forces scratch spill (R15: 40->192us).
__global__ __launch_bounds__(256, 2)
void k_attention(const short* __restrict__ Qbf, const short* __restrict__ Kbf,
                 const short* __restrict__ VT, const char* __restrict__ allowC,
                 short* __restrict__ Obf) {
  __shared__ __align__(16) short Plds[4][32][72];  // per-wave P: [q][key]
  __shared__ float maskF[Nn];                      // 0 or -1e30 per key
  int bid = blockIdx.x;
  int h = bid & 7, b = (bid >> 3) & 7, qt = bid >> 6;  // qt in [0,8)
  int tid = threadIdx.x, w = tid >> 6, lane = tid & 63, lr = lane & 15, lg = lane >> 4;
  int q0 = qt * 128 + w * 32;   // this wave's first q row

  {
    const char* ac = allowC + b * Nn;
    #pragma unroll
    for (int j = 0; j < 4; j++) {
      int i = tid * 4 + j;
      maskF[i] = ac[i] ? 0.0f : -1e30f;
    }
  }
  __syncthreads();

  // Q fragments: 2 sub-tiles of 16 rows
  bf16x8 aq[2][2];
  #pragma unroll
  for (int qi = 0; qi < 2; qi++)
  #pragma unroll
  for (int j = 0; j < 2; j++)
    aq[qi][j] = *(const bf16x8*)(Qbf + swz(b * Nn + q0 + qi * 16 + lr,
                                           h * 64 + j * 32 + lg * 8, Dd));
  f32x4 acco[2][4] = {};
  float m_run[2][4], l_run[2][4];
  #pragma unroll
  for (int qi = 0; qi < 2; qi++)
  #pragma unroll
  for (int r = 0; r < 4; r++) { m_run[qi][r] = 0.0f; l_run[qi][r] = 0.0f; }
  const float scale2 = 0.06375871573f;  // (1/sqrt(512)) * log2(e)

  auto loadK = [&](bf16x8 (&kf)[4][2], int kb) {
    #pragma unroll
    for (int sub = 0; sub < 4; sub++)
    #pragma unroll
    for (int j = 0; j < 2; j++)
      kf[sub][j] = *(const bf16x8*)(Kbf + swz(b * Nn + kb + sub * 16 + lr,
                                              h * 64 + j * 32 + lg * 8, Dd));
  };

  auto process = [&](bf16x8 (&kf)[4][2], int kb, bf16x8 (&kfn)[4][2], int kbn) {
    loadK(kfn, kbn);                       // prefetch next K tile
    bf16x8 vb[2][4];                       // V^T frags for THIS tile, issued early
    #pragma unroll
    for (int ks = 0; ks < 2; ks++)
    #pragma unroll
    for (int t = 0; t < 4; t++)
      vb[ks][t] = *(const bf16x8*)(VT + swz(h * 64 + t * 16 + lr,
                                            b * Nn + kb + ks * 32 + lg * 8, Mrows));
    // S = Q K^T (log2-domain scores)
    f32x4 accs[2][4] = {};
    #pragma unroll
    for (int sub = 0; sub < 4; sub++) {
      #pragma unroll
      for (int qi = 0; qi < 2; qi++) {
        accs[qi][sub] = mfma16(aq[qi][0], kf[sub][0], accs[qi][sub]);
        accs[qi][sub] = mfma16(aq[qi][1], kf[sub][1], accs[qi][sub]);
      }
    }
    float mk[4];
    #pragma unroll
    for (int sub = 0; sub < 4; sub++) mk[sub] = maskF[kb + sub * 16 + lr];
    float sv[2][4][4];
    #pragma unroll
    for (int qi = 0; qi < 2; qi++)
    #pragma unroll
    for (int sub = 0; sub < 4; sub++)
    #pragma unroll
    for (int r = 0; r < 4; r++)
      sv[qi][sub][r] = accs[qi][sub][r] * scale2 + mk[sub];
    // diagonal always attendable -- only in the tile containing this wave's rows
    if (kb == (q0 & ~63)) {
      #pragma unroll
      for (int qi = 0; qi < 2; qi++)
      #pragma unroll
      for (int sub = 0; sub < 4; sub++) {
        int key = kb + sub * 16 + lr;
        #pragma unroll
        for (int r = 0; r < 4; r++) {
          int qrow = q0 + qi * 16 + lg * 4 + r;
          if (key == qrow) sv[qi][sub][r] = accs[qi][sub][r] * scale2;
        }
      }
    }
    // defer-max (log2 domain: THR = 8*log2e)
    bool allok = true;
    float pmax[2][4];
    #pragma unroll
    for (int qi = 0; qi < 2; qi++)
    #pragma unroll
    for (int r = 0; r < 4; r++) {
      pmax[qi][r] = fmaxf(fmaxf(sv[qi][0][r], sv[qi][1][r]),
                          fmaxf(sv[qi][2][r], sv[qi][3][r]));
      allok = allok && (pmax[qi][r] <= m_run[qi][r] + 11.5416f);
    }
    if (!__all(allok)) {
      #pragma unroll
      for (int qi = 0; qi < 2; qi++)
      #pragma unroll
      for (int r = 0; r < 4; r++) {
        float m = pmax[qi][r];
        #pragma unroll
        for (int off = 1; off < 16; off <<= 1) m = fmaxf(m, __shfl_xor(m, off));
        float mtot = fmaxf(m_run[qi][r], m);
        float alpha = fexp2(m_run[qi][r] - mtot);
        l_run[qi][r] *= alpha;
        m_run[qi][r] = mtot;
        #pragma unroll
        for (int t = 0; t < 4; t++) acco[qi][t][r] *= alpha;
      }
    }
    // exps + P write (per-lane partial l sums; reduced in epilogue)
    #pragma unroll
    for (int qi = 0; qi < 2; qi++)
    #pragma unroll
    for (int sub = 0; sub < 4; sub++)
    #pragma unroll
    for (int r = 0; r < 4; r++) {
      float e = fexp2(sv[qi][sub][r] - m_run[qi][r]);
      l_run[qi][r] += e;
      Plds[w][qi * 16 + lg * 4 + r][sub * 16 + lr] = f2bf(e);
    }
    // O += P @ V
    #pragma unroll
    for (int ks = 0; ks < 2; ks++) {
      bf16x8 pa0 = *(const bf16x8*)(&Plds[w][lr][ks * 32 + lg * 8]);
      bf16x8 pa1 = *(const bf16x8*)(&Plds[w][16 + lr][ks * 32 + lg * 8]);
      #pragma unroll
      for (int t = 0; t < 4; t++) {
        acco[0][t] = mfma16(pa0, vb[ks][t], acco[0][t]);
        acco[1][t] = mfma16(pa1, vb[ks][t], acco[1][t]);
      }
    }
  };

  bf16x8 kfA[4][2], kfB[4][2];
  loadK(kfA, 0);
  for (int kb = 0; kb < Nn; kb += 128) {
    int n1 = kb + 64;
    int n2 = (kb + 128 < Nn) ? (kb + 128) : 0;
    process(kfA, kb, kfB, n1);
    process(kfB, n1, kfA, n2);
  }

  // epilogue: reduce l across the 16-lane group, divide, write bf16 O (swz)
  #pragma unroll
  for (int qi = 0; qi < 2; qi++)
  #pragma unroll
  for (int r = 0; r < 4; r++) {
    float lsum = l_run[qi][r];
    #pragma unroll
    for (int off = 1; off < 16; off <<= 1) lsum += __shfl_xor(lsum, off);
    l_run[qi][r] = lsum;
  }
  #pragma unroll
  for (int qi = 0; qi < 2; qi++)
  #pragma unroll
  for (int t = 0; t < 4; t++)
  #pragma unroll
  for (int r = 0; r < 4; r++) {
    int q = b * Nn + q0 + qi * 16 + lg * 4 + r;
    Obf[swz(q, h * 64 + t * 16 + lr, Dd)] = f2bf(acco[qi][t][r] / l_run[qi][r]);
  }
}

// ---------------------------------------------------------------------------
extern "C" void kernel_launch(void* const* d_in, const int* in_sizes, int n_in,
                              void* d_out, int out_size, void* d_ws, size_t ws_size,
                              hipStream_t stream) {
  const float* X    = (const float*)d_in[0];
  const int*   train= (const int*)d_in[1];
  const int*   batch= (const int*)d_in[2];
  const float* Wq   = (const float*)d_in[3];
  const float* bq   = (const float*)d_in[4];
  const float* Wk   = (const float*)d_in[5];
  const float* bk   = (const float*)d_in[6];
  const float* Wv   = (const float*)d_in[7];
  const float* bv   = (const float*)d_in[8];
  const float* Wmix = (const float*)d_in[9];
  const float* bmix = (const float*)d_in[10];
  const float* ln0s = (const float*)d_in[11];
  const float* ln0b = (const float*)d_in[12];
  const float* ln1s = (const float*)d_in[13];
  const float* ln1b = (const float*)d_in[14];
  const float* wi0  = (const float*)d_in[15];
  const float* wi1  = (const float*)d_in[16];
  const float* wo   = (const float*)d_in[17];
  float* out = (float*)d_out;

  char* ws = (char*)d_ws;
  size_t off = 0;
  auto alloc = [&](size_t bytes) {
    off = (off + 255) & ~(size_t)255;
    void* p = ws + off; off += bytes; return p;
  };
  short* Xbf   = (short*)alloc((size_t)Mrows * Dd * 2);
  short* Xnbf  = (short*)alloc((size_t)Mrows * Dd * 2);
  short* Qbf   = (short*)alloc((size_t)Mrows * Dd * 2);
  short* Kbf   = (short*)alloc((size_t)Mrows * Dd * 2);
  short* VTg   = (short*)alloc((size_t)Dd * Mrows * 2);   // V^T swz [Dd][Mrows]
  short* Obf   = (short*)alloc((size_t)Mrows * Dd * 2);
  short* x1bf  = (short*)alloc((size_t)Mrows * Dd * 2);
  short* FFbf  = (short*)alloc((size_t)Mrows * FFd * 2);
  short* Hcbf  = (short*)alloc((size_t)Mrows * Dd * 2);   // Hc bf16 swz
  short* WqT   = (short*)alloc((size_t)Dd * Dd * 2);
  short* WkT   = (short*)alloc((size_t)Dd * Dd * 2);
  short* WvT   = (short*)alloc((size_t)Dd * Dd * 2);
  short* WmixT = (short*)alloc((size_t)Dd * Dd * 2);
  short* wi0T  = (short*)alloc((size_t)FFd * Dd * 2);
  short* wi1T  = (short*)alloc((size_t)FFd * Dd * 2);
  short* woT   = (short*)alloc((size_t)Dd * FFd * 2);
  char*  allowC= (char*)alloc((size_t)Mrows);

  dim3 blk(256);
  // transposes + mask + LN0 in one dispatch (6176 blocks)
  PreArgs pa;
  pa.src[0] = Wq;   pa.dst[0] = WqT;
  pa.src[1] = Wk;   pa.dst[1] = WkT;
  pa.src[2] = Wv;   pa.dst[2] = WvT;
  pa.src[3] = Wmix; pa.dst[3] = WmixT;
  pa.src[4] = wi0;  pa.dst[4] = wi0T;
  pa.src[5] = wi1;  pa.dst[5] = wi1T;
  pa.src[6] = wo;   pa.dst[6] = woT;
  pa.train = train; pa.batch = batch; pa.allowC = allowC;
  pa.X = X; pa.sc = ln0s; pa.bi = ln0b; pa.xn = Xnbf; pa.xraw = Xbf;
  k_preprocess<<<6176, blk, 0, stream>>>(pa);

  // Q, K, V^T in one dispatch (1536 blocks, BK=32 -> 6 blocks/CU resident)
  k_qkv<<<1536, blk, 0, stream>>>(Xnbf, Xbf, WqT, WkT, WvT, bq, bk, bv,
                                  Qbf, Kbf, VTg);

  // attention (128 q-rows per block, grid 512, XCD-pinned per head)
  k_attention<<<Bb * Hh * (Nn / 128), blk, 0, stream>>>(Qbf, Kbf, VTg, allowC, Obf);

  // Hc = O @ Wmix + bmix + Q -> bf16 swz (residual from bf16 Qbf)
  k_gemm128<64, 64, 1, 2, false, true><<<dim3(Dd / 64, Mrows / 128), blk, 0, stream>>>(
      Obf, WmixT, bmix, nullptr, Qbf, nullptr, Hcbf, Mrows, Dd, Dd);

  // LN1 (reads bf16 swz Hc)
  k_layernorm1<<<Mrows / 4, blk, 0, stream>>>(Hcbf, ln1s, ln1b, x1bf);

  // FF = gelu(x1@wi0) * (x1@wi1), fused dual-acc BN=64 (2048 blocks)
  k_geglu64<<<2048, blk, 0, stream>>>(x1bf, wi0T, wi1T, FFbf);

  // out = Hc + FF @ wo  -- BK=64, residual from bf16 Hcbf
  k_gemm128<64, 64, 0, 2, true, false><<<dim3(Dd / 64, Mrows / 128), blk, 0, stream>>>(
      FFbf, woT, nullptr, nullptr, Hcbf, out, nullptr, Mrows, Dd, FFd);
}

// Round 25
// 170.446 us; speedup vs baseline: 1.0029x; 1.0029x over previous
//
#include <hip/hip_runtime.h>
#include <hip/hip_bf16.h>
#include <math.h>

#define DEV __device__ __forceinline__

using bf16x8 = __attribute__((ext_vector_type(8))) short;
using f32x4  = __attribute__((ext_vector_type(4))) float;

static constexpr int Bb = 8, Nn = 1024, Dd = 512, Hh = 8, DHd = 64, FFd = 2048;
static constexpr int Mrows = Bb * Nn; // 8192

DEV short f2bf(float f) {
  union { float f; unsigned u; } v; v.f = f;
  unsigned r = v.u + 0x7fffu + ((v.u >> 16) & 1u);
  return (short)(r >> 16);
}
DEV float bf2f(short s) {
  union { unsigned u; float f; } v; v.u = ((unsigned)(unsigned short)s) << 16;
  return v.f;
}
DEV float fexp2(float x) { return __builtin_amdgcn_exp2f(x); }

DEV f32x4 mfma16(bf16x8 a, bf16x8 b, f32x4 c) {
  return __builtin_amdgcn_mfma_f32_16x16x32_bf16(a, b, c, 0, 0, 0);
}

// swizzle64 layout for all bf16 operand buffers:
// element (row r, col k, leading-dim ld) lives at
//   (r>>6)*64*ld + (k>>3)*512 + (r&63)*8 + (k&7)
DEV size_t swz(int r, int k, int ld) {
  return (size_t)(r >> 6) * 64 * ld + (size_t)(k >> 3) * 512
       + (size_t)((r & 63) * 8 + (k & 7));
}

// async global->LDS, 16B per lane. LDS dest is wave-uniform base + lane*16.
DEV void gload16(const void* g, void* l) {
  __builtin_amdgcn_global_load_lds(
      (const __attribute__((address_space(1))) void*)g,
      (__attribute__((address_space(3))) void*)l, 16, 0, 0);
}

// gelu_new(g) = g * sigmoid(2 * 0.79788456 * (g + 0.044715 g^3)), exp2 domain
DEV float gelu_fast(float g) {
  float u2l = 2.30220822f * (g + 0.044715f * g * g * g); // 2*0.79788456*log2e
  return g / (1.0f + fexp2(-u2l));
}

// 2-D per-XCD chunk swizzle (flat wg within a (gx,gy) tile grid).
DEV void xcd_tile2(int wg, int gx, int gy, int& trow, int& tcol) {
  int xcd = wg & 7, idx = wg >> 3;
  int XC = (gx >= 16) ? 2 : 1, XR = 8 / XC;
  int lcx = gx / XC, lcy = gy / XR;
  trow = (xcd / XC) * lcy + idx / lcx;
  tcol = (xcd % XC) * lcx + idx % lcx;
}

// ---------------- merged preprocess: 7 transposes + mask + LN0 --------------
struct PreArgs {
  const float* src[7]; short* dst[7];
  const int* train; const int* batch; char* allowC;
  const float* X; const float* sc; const float* bi;
  short* xn; short* xraw;
};
__global__ __launch_bounds__(256)
void k_preprocess(PreArgs a) {
  __shared__ float tile[32][33];
  int id = blockIdx.x;
  if (id < 4096) {
    int j, rem;
    if (id < 1024)      { j = id >> 8;                 rem = id & 255; }
    else if (id < 3072) { j = 4 + ((id - 1024) >> 10); rem = (id - 1024) & 1023; }
    else                { j = 6;                       rem = id - 3072; }
    int K = (j == 6) ? 2048 : 512;
    int N = (j == 4 || j == 5) ? 2048 : 512;
    const float* W = a.src[j];
    short* WT = a.dst[j];
    int gx = N >> 5;
    int nb = (rem % gx) * 32, kb = (rem / gx) * 32;
    int tx = threadIdx.x & 31, ty = threadIdx.x >> 5;
    #pragma unroll
    for (int i = ty; i < 32; i += 8)
      tile[i][tx] = W[(size_t)(kb + i) * N + nb + tx];
    __syncthreads();
    #pragma unroll
    for (int i = ty; i < 32; i += 8)
      WT[swz(nb + i, kb + tx, K)] = f2bf(tile[tx][i]);
  } else if (id < 4128) {
    int i = (id - 4096) * 256 + threadIdx.x;
    a.allowC[i] = ((a.train[i] | a.batch[i]) != 0) ? 1 : 0;
  } else {
    int w = threadIdx.x >> 6, lane = threadIdx.x & 63;
    int row = (id - 4128) * 4 + w;
    const float* x = a.X + (size_t)row * Dd + lane * 8;
    f32x4 va = *(const f32x4*)x;
    f32x4 vb = *(const f32x4*)(x + 4);
    float p = va[0] + va[1] + va[2] + va[3] + vb[0] + vb[1] + vb[2] + vb[3];
    #pragma unroll
    for (int off = 1; off < 64; off <<= 1) p += __shfl_xor(p, off);
    float mean = p * (1.0f / Dd);
    float d[8];
    #pragma unroll
    for (int j = 0; j < 4; j++) { d[j] = va[j] - mean; d[4 + j] = vb[j] - mean; }
    float q = 0.0f;
    #pragma unroll
    for (int j = 0; j < 8; j++) q += d[j] * d[j];
    #pragma unroll
    for (int off = 1; off < 64; off <<= 1) q += __shfl_xor(q, off);
    float rs = rsqrtf(q * (1.0f / Dd) + 1e-12f);
    int c0 = lane * 8;
    f32x4 s0 = *(const f32x4*)(a.sc + c0), s1 = *(const f32x4*)(a.sc + c0 + 4);
    f32x4 b0 = *(const f32x4*)(a.bi + c0), b1 = *(const f32x4*)(a.bi + c0 + 4);
    bf16x8 o;
    #pragma unroll
    for (int j = 0; j < 4; j++) {
      o[j]     = f2bf(d[j] * rs * s0[j] + b0[j]);
      o[4 + j] = f2bf(d[4 + j] * rs * s1[j] + b1[j]);
    }
    *(bf16x8*)(a.xn + swz(row, c0, Dd)) = o;
    bf16x8 rv;
    #pragma unroll
    for (int j = 0; j < 4; j++) { rv[j] = f2bf(va[j]); rv[4 + j] = f2bf(vb[j]); }
    *(bf16x8*)(a.xraw + swz(row, c0, Dd)) = rv;
  }
}

// ---------------- layernorm for LN1: reads bf16 swz Hc, one row per WAVE ----
__global__ __launch_bounds__(256)
void k_layernorm1(const short* __restrict__ Xb, const float* __restrict__ sc,
                  const float* __restrict__ bi, short* __restrict__ out) {
  int w = threadIdx.x >> 6, lane = threadIdx.x & 63;
  int row = blockIdx.x * 4 + w;
  int c0 = lane * 8;
  bf16x8 v = *(const bf16x8*)(Xb + swz(row, c0, Dd));
  float vals[8];
  #pragma unroll
  for (int j = 0; j < 8; j++) vals[j] = bf2f(v[j]);
  float p = 0.0f;
  #pragma unroll
  for (int j = 0; j < 8; j++) p += vals[j];
  #pragma unroll
  for (int off = 1; off < 64; off <<= 1) p += __shfl_xor(p, off);
  float mean = p * (1.0f / Dd);
  float d[8];
  #pragma unroll
  for (int j = 0; j < 8; j++) d[j] = vals[j] - mean;
  float q = 0.0f;
  #pragma unroll
  for (int j = 0; j < 8; j++) q += d[j] * d[j];
  #pragma unroll
  for (int off = 1; off < 64; off <<= 1) q += __shfl_xor(q, off);
  float rs = rsqrtf(q * (1.0f / Dd) + 1e-12f);
  f32x4 s0 = *(const f32x4*)(sc + c0), s1 = *(const f32x4*)(sc + c0 + 4);
  f32x4 b0 = *(const f32x4*)(bi + c0), b1 = *(const f32x4*)(bi + c0 + 4);
  bf16x8 o;
  #pragma unroll
  for (int j = 0; j < 4; j++) {
    o[j]     = f2bf(d[j] * rs * s0[j] + b0[j]);
    o[4 + j] = f2bf(d[4 + j] * rs * s1[j] + b1[j]);
  }
  *(bf16x8*)(out + swz(row, c0, Dd)) = o;
}

// ---------------- LDS-staged bf16 MFMA GEMM: C = A[M][K] @ BT[N][K]^T -------
// A/BT in swz layout. 128 x BN tile, BK k-depth, 4 waves, 2-buf stage-ahead.
// BIASM: 0 none, 1 bias[col], 2 bias[row].
// RESM:  0 none, 1 f32 row-major, 2 bf16 swz.
template<int BN, int BK, int BIASM, int RESM, bool WF, bool WB>
__global__ __launch_bounds__(256, 4)
void k_gemm128(const short* __restrict__ A, const short* __restrict__ BT,
               const float* __restrict__ bias, const float* __restrict__ resF,
               const short* __restrict__ resB,
               float* __restrict__ outF, short* __restrict__ outB,
               int M, int N, int K) {
  constexpr int FN = BN / 32;   // frag cols per wave
  __shared__ short lA[2][128 * BK];
  __shared__ short lB[2][BN * BK];
  int tid = threadIdx.x, w = tid >> 6, lane = tid & 63;
  int lr = lane & 15, lg = lane >> 4;
  int wr = w >> 1, wc = w & 1;
  int trow, tcol;
  xcd_tile2(blockIdx.y * gridDim.x + blockIdx.x, gridDim.x, gridDim.y, trow, tcol);
  int row0 = trow * 128, col0 = tcol * BN;
  f32x4 acc[4][FN] = {};

  auto stage = [&](int buf, int k0) {
    #pragma unroll
    for (int i = 0; i < BK / 16; i++) {
      int c = i * 4 + w;
      gload16(A + swz(row0 + (c & 1) * 64 + lane, k0 + (c >> 1) * 8, K),
              &lA[buf][c * 512]);
    }
    #pragma unroll
    for (int i = 0; i < (BN * BK) / 2048; i++) {
      int c = i * 4 + w;
      if (BN == 128)
        gload16(BT + swz(col0 + (c & 1) * 64 + lane, k0 + (c >> 1) * 8, K),
                &lB[buf][c * 512]);
      else
        gload16(BT + swz(col0 + lane, k0 + c * 8, K), &lB[buf][c * 512]);
    }
  };

  stage(0, 0);
  __syncthreads();
  int nt = K / BK, buf = 0;
  for (int t = 0; t < nt; t++) {
    if (t + 1 < nt) stage(buf ^ 1, (t + 1) * BK);
    #pragma unroll
    for (int kk = 0; kk < BK / 32; kk++) {
      bf16x8 af[4];
      #pragma unroll
      for (int m = 0; m < 4; m++)
        af[m] = *(const bf16x8*)&lA[buf][(kk * 4 + lg) * 1024 + (wr * 64 + m * 16 + lr) * 8];
      #pragma unroll
      for (int n = 0; n < FN; n++) {
        bf16x8 bfr = *(const bf16x8*)&lB[buf][(kk * 4 + lg) * (BN * 8)
                                              + (wc * (BN / 2) + n * 16 + lr) * 8];
        #pragma unroll
        for (int m = 0; m < 4; m++)
          acc[m][n] = mfma16(af[m], bfr, acc[m][n]);
      }
    }
    __syncthreads();
    buf ^= 1;
  }

  #pragma unroll
  for (int n = 0; n < FN; n++) {
    int col = col0 + wc * (BN / 2) + n * 16 + lr;
    float bv = (BIASM == 1) ? bias[col] : 0.0f;
    #pragma unroll
    for (int m = 0; m < 4; m++) {
      #pragma unroll
      for (int r = 0; r < 4; r++) {
        int rowg = row0 + wr * 64 + m * 16 + lg * 4 + r;
        float vv = acc[m][n][r] + bv;
        if (BIASM == 2) vv += bias[rowg];
        if (RESM == 1) vv += resF[(size_t)rowg * N + col];
        if (RESM == 2) vv += bf2f(resB[swz(rowg, col, N)]);
        if (WF) outF[(size_t)rowg * N + col] = vv;
        if (WB) outB[swz(rowg, col, N)] = f2bf(vv);
      }
    }
  }
}

// ---------------- fused GEGLU, BN=64 dual-acc: FF = gelu(x1@wi0^T)*(x1@wi1^T)
// M=8192, N=2048, K=512, BK=32. LDS 32KB, acc 64 VGPR.
// launch_bounds (256,4): do NOT tighten to (256,5) -- the ~96-VGPR cap spills
// the accumulators to scratch (R22: 46->210us, FETCH 30->270MB).
__global__ __launch_bounds__(256, 4)
void k_geglu64(const short* __restrict__ A, const short* __restrict__ BT0,
               const short* __restrict__ BT1, short* __restrict__ outB) {
  constexpr int BN = 64, BK = 32, K = 512, N = 2048;
  __shared__ short lA[2][128 * BK];
  __shared__ short lB0[2][BN * BK];
  __shared__ short lB1[2][BN * BK];
  int tid = threadIdx.x, w = tid >> 6, lane = tid & 63;
  int lr = lane & 15, lg = lane >> 4;
  int wr = w >> 1, wc = w & 1;
  int trow, tcol;
  xcd_tile2(blockIdx.x, N / BN, Mrows / 128, trow, tcol);
  int row0 = trow * 128, col0 = tcol * BN;
  f32x4 acc0[4][2] = {}, acc1[4][2] = {};

  auto stage = [&](int buf, int k0) {
    #pragma unroll
    for (int i = 0; i < 2; i++) {           // A: 8 chunks of 1KB
      int c = i * 4 + w;
      gload16(A + swz(row0 + (c & 1) * 64 + lane, k0 + (c >> 1) * 8, K),
              &lA[buf][c * 512]);
    }
    {
      int c = w;                            // B0, B1: 4 chunks each
      gload16(BT0 + swz(col0 + lane, k0 + c * 8, K), &lB0[buf][c * 512]);
      gload16(BT1 + swz(col0 + lane, k0 + c * 8, K), &lB1[buf][c * 512]);
    }
  };

  stage(0, 0);
  __syncthreads();
  int nt = K / BK, buf = 0;
  for (int t = 0; t < nt; t++) {
    if (t + 1 < nt) stage(buf ^ 1, (t + 1) * BK);
    bf16x8 af[4];
    #pragma unroll
    for (int m = 0; m < 4; m++)
      af[m] = *(const bf16x8*)&lA[buf][lg * 1024 + (wr * 64 + m * 16 + lr) * 8];
    #pragma unroll
    for (int n = 0; n < 2; n++) {
      bf16x8 b0 = *(const bf16x8*)&lB0[buf][lg * (BN * 8) + (wc * 32 + n * 16 + lr) * 8];
      #pragma unroll
      for (int m = 0; m < 4; m++)
        acc0[m][n] = mfma16(af[m], b0, acc0[m][n]);
      bf16x8 b1 = *(const bf16x8*)&lB1[buf][lg * (BN * 8) + (wc * 32 + n * 16 + lr) * 8];
      #pragma unroll
      for (int m = 0; m < 4; m++)
        acc1[m][n] = mfma16(af[m], b1, acc1[m][n]);
    }
    __syncthreads();
    buf ^= 1;
  }

  #pragma unroll
  for (int n = 0; n < 2; n++) {
    int col = col0 + wc * 32 + n * 16 + lr;
    #pragma unroll
    for (int m = 0; m < 4; m++) {
      #pragma unroll
      for (int r = 0; r < 4; r++) {
        int rowg = row0 + wr * 64 + m * 16 + lg * 4 + r;
        outB[swz(rowg, col, N)] = f2bf(gelu_fast(acc0[m][n][r]) * acc1[m][n][r]);
      }
    }
  }
}

// ---------------- merged Q/K/V^T GEMMs: one dispatch, 1536 blocks -----------
// BK=32: LDS 24KB -> 6 blocks/CU resident (grid gives 6 blocks/CU of work).
__global__ __launch_bounds__(256, 4)
void k_qkv(const short* __restrict__ Xnbf, const short* __restrict__ Xbf,
           const short* __restrict__ WqT, const short* __restrict__ WkT,
           const short* __restrict__ WvT,
           const float* __restrict__ bq, const float* __restrict__ bk,
           const float* __restrict__ bv,
           short* __restrict__ Qbf, short* __restrict__ Kbf,
           short* __restrict__ VTg) {
  constexpr int BN = 64, BK = 32, FN = 2;
  constexpr int K = 512;
  __shared__ short lA[2][128 * BK];
  __shared__ short lB[2][BN * BK];
  int id = blockIdx.x;
  int which = id >> 9, sub = id & 511;
  const short *A, *BT; const float* bias; short* outB;
  int N, gx, gy; bool rowbias;
  if (which == 0)      { A = Xnbf; BT = WqT; bias = bq; outB = Qbf; N = 512;  gx = 8;   gy = 64; rowbias = false; }
  else if (which == 1) { A = Xbf;  BT = WkT; bias = bk; outB = Kbf; N = 512;  gx = 8;   gy = 64; rowbias = false; }
  else                 { A = WvT;  BT = Xbf; bias = bv; outB = VTg; N = 8192; gx = 128; gy = 4;  rowbias = true;  }
  int tid = threadIdx.x, w = tid >> 6, lane = tid & 63;
  int lr = lane & 15, lg = lane >> 4;
  int wr = w >> 1, wc = w & 1;
  int trow, tcol;
  xcd_tile2(sub, gx, gy, trow, tcol);
  int row0 = trow * 128, col0 = tcol * BN;
  f32x4 acc[4][FN] = {};

  auto stage = [&](int buf, int k0) {
    #pragma unroll
    for (int i = 0; i < 2; i++) {          // A: 8 chunks of 1KB
      int c = i * 4 + w;
      gload16(A + swz(row0 + (c & 1) * 64 + lane, k0 + (c >> 1) * 8, K),
              &lA[buf][c * 512]);
    }
    {
      int c = w;                           // B: 4 chunks
      gload16(BT + swz(col0 + lane, k0 + c * 8, K), &lB[buf][c * 512]);
    }
  };

  stage(0, 0);
  __syncthreads();
  int nt = K / BK, buf = 0;
  for (int t = 0; t < nt; t++) {
    if (t + 1 < nt) stage(buf ^ 1, (t + 1) * BK);
    bf16x8 af[4];
    #pragma unroll
    for (int m = 0; m < 4; m++)
      af[m] = *(const bf16x8*)&lA[buf][lg * 1024 + (wr * 64 + m * 16 + lr) * 8];
    #pragma unroll
    for (int n = 0; n < FN; n++) {
      bf16x8 bfr = *(const bf16x8*)&lB[buf][lg * (BN * 8)
                                            + (wc * (BN / 2) + n * 16 + lr) * 8];
      #pragma unroll
      for (int m = 0; m < 4; m++)
        acc[m][n] = mfma16(af[m], bfr, acc[m][n]);
    }
    __syncthreads();
    buf ^= 1;
  }

  #pragma unroll
  for (int n = 0; n < FN; n++) {
    int col = col0 + wc * (BN / 2) + n * 16 + lr;
    float bvc = rowbias ? 0.0f : bias[col];
    #pragma unroll
    for (int m = 0; m < 4; m++) {
      #pragma unroll
      for (int r = 0; r < 4; r++) {
        int rowg = row0 + wr * 64 + m * 16 + lg * 4 + r;
        float vv = acc[m][n][r] + bvc;
        if (rowbias) vv += bias[rowg];
        outB[swz(rowg, col, N)] = f2bf(vv);
      }
    }
  }
}

// ---------------- flash attention, 128 q-rows/block, exp2-domain softmax ----
// Qbf/Kbf swz over [Mrows][Dd]; VT swz over [Dd][Mrows].
// grid 512; launch_bounds (256,2) -- do NOT tighten to (256,4): live state
// needs ~150 VGPR at peak, a 128 cap forces scratch spill (R15: 40->192us).
// T5: setprio(1) around MFMA clusters -- waves here are barrier-free and at
// different phases, so the CU scheduler can favor the matrix-pipe wave (m191).
__global__ __launch_bounds__(256, 2)
void k_attention(const short* __restrict__ Qbf, const short* __restrict__ Kbf,
                 const short* __restrict__ VT, const char* __restrict__ allowC,
                 short* __restrict__ Obf) {
  __shared__ __align__(16) short Plds[4][32][72];  // per-wave P: [q][key]
  __shared__ float maskF[Nn];                      // 0 or -1e30 per key
  int bid = blockIdx.x;
  int h = bid & 7, b = (bid >> 3) & 7, qt = bid >> 6;  // qt in [0,8)
  int tid = threadIdx.x, w = tid >> 6, lane = tid & 63, lr = lane & 15, lg = lane >> 4;
  int q0 = qt * 128 + w * 32;   // this wave's first q row

  {
    const char* ac = allowC + b * Nn;
    #pragma unroll
    for (int j = 0; j < 4; j++) {
      int i = tid * 4 + j;
      maskF[i] = ac[i] ? 0.0f : -1e30f;
    }
  }
  __syncthreads();

  // Q fragments: 2 sub-tiles of 16 rows
  bf16x8 aq[2][2];
  #pragma unroll
  for (int qi = 0; qi < 2; qi++)
  #pragma unroll
  for (int j = 0; j < 2; j++)
    aq[qi][j] = *(const bf16x8*)(Qbf + swz(b * Nn + q0 + qi * 16 + lr,
                                           h * 64 + j * 32 + lg * 8, Dd));
  f32x4 acco[2][4] = {};
  float m_run[2][4], l_run[2][4];
  #pragma unroll
  for (int qi = 0; qi < 2; qi++)
  #pragma unroll
  for (int r = 0; r < 4; r++) { m_run[qi][r] = 0.0f; l_run[qi][r] = 0.0f; }
  const float scale2 = 0.06375871573f;  // (1/sqrt(512)) * log2(e)

  auto loadK = [&](bf16x8 (&kf)[4][2], int kb) {
    #pragma unroll
    for (int sub = 0; sub < 4; sub++)
    #pragma unroll
    for (int j = 0; j < 2; j++)
      kf[sub][j] = *(const bf16x8*)(Kbf + swz(b * Nn + kb + sub * 16 + lr,
                                              h * 64 + j * 32 + lg * 8, Dd));
  };

  auto process = [&](bf16x8 (&kf)[4][2], int kb, bf16x8 (&kfn)[4][2], int kbn) {
    loadK(kfn, kbn);                       // prefetch next K tile
    bf16x8 vb[2][4];                       // V^T frags for THIS tile, issued early
    #pragma unroll
    for (int ks = 0; ks < 2; ks++)
    #pragma unroll
    for (int t = 0; t < 4; t++)
      vb[ks][t] = *(const bf16x8*)(VT + swz(h * 64 + t * 16 + lr,
                                            b * Nn + kb + ks * 32 + lg * 8, Mrows));
    // S = Q K^T (log2-domain scores)
    f32x4 accs[2][4] = {};
    __builtin_amdgcn_s_setprio(1);
    #pragma unroll
    for (int sub = 0; sub < 4; sub++) {
      #pragma unroll
      for (int qi = 0; qi < 2; qi++) {
        accs[qi][sub] = mfma16(aq[qi][0], kf[sub][0], accs[qi][sub]);
        accs[qi][sub] = mfma16(aq[qi][1], kf[sub][1], accs[qi][sub]);
      }
    }
    __builtin_amdgcn_s_setprio(0);
    float mk[4];
    #pragma unroll
    for (int sub = 0; sub < 4; sub++) mk[sub] = maskF[kb + sub * 16 + lr];
    float sv[2][4][4];
    #pragma unroll
    for (int qi = 0; qi < 2; qi++)
    #pragma unroll
    for (int sub = 0; sub < 4; sub++)
    #pragma unroll
    for (int r = 0; r < 4; r++)
      sv[qi][sub][r] = accs[qi][sub][r] * scale2 + mk[sub];
    // diagonal always attendable -- only in the tile containing this wave's rows
    if (kb == (q0 & ~63)) {
      #pragma unroll
      for (int qi = 0; qi < 2; qi++)
      #pragma unroll
      for (int sub = 0; sub < 4; sub++) {
        int key = kb + sub * 16 + lr;
        #pragma unroll
        for (int r = 0; r < 4; r++) {
          int qrow = q0 + qi * 16 + lg * 4 + r;
          if (key == qrow) sv[qi][sub][r] = accs[qi][sub][r] * scale2;
        }
      }
    }
    // defer-max (log2 domain: THR = 8*log2e)
    bool allok = true;
    float pmax[2][4];
    #pragma unroll
    for (int qi = 0; qi < 2; qi++)
    #pragma unroll
    for (int r = 0; r < 4; r++) {
      pmax[qi][r] = fmaxf(fmaxf(sv[qi][0][r], sv[qi][1][r]),
                          fmaxf(sv[qi][2][r], sv[qi][3][r]));
      allok = allok && (pmax[qi][r] <= m_run[qi][r] + 11.5416f);
    }
    if (!__all(allok)) {
      #pragma unroll
      for (int qi = 0; qi < 2; qi++)
      #pragma unroll
      for (int r = 0; r < 4; r++) {
        float m = pmax[qi][r];
        #pragma unroll
        for (int off = 1; off < 16; off <<= 1) m = fmaxf(m, __shfl_xor(m, off));
        float mtot = fmaxf(m_run[qi][r], m);
        float alpha = fexp2(m_run[qi][r] - mtot);
        l_run[qi][r] *= alpha;
        m_run[qi][r] = mtot;
        #pragma unroll
        for (int t = 0; t < 4; t++) acco[qi][t][r] *= alpha;
      }
    }
    // exps + P write (per-lane partial l sums; reduced in epilogue)
    #pragma unroll
    for (int qi = 0; qi < 2; qi++)
    #pragma unroll
    for (int sub = 0; sub < 4; sub++)
    #pragma unroll
    for (int r = 0; r < 4; r++) {
      float e = fexp2(sv[qi][sub][r] - m_run[qi][r]);
      l_run[qi][r] += e;
      Plds[w][qi * 16 + lg * 4 + r][sub * 16 + lr] = f2bf(e);
    }
    // O += P @ V
    __builtin_amdgcn_s_setprio(1);
    #pragma unroll
    for (int ks = 0; ks < 2; ks++) {
      bf16x8 pa0 = *(const bf16x8*)(&Plds[w][lr][ks * 32 + lg * 8]);
      bf16x8 pa1 = *(const bf16x8*)(&Plds[w][16 + lr][ks * 32 + lg * 8]);
      #pragma unroll
      for (int t = 0; t < 4; t++) {
        acco[0][t] = mfma16(pa0, vb[ks][t], acco[0][t]);
        acco[1][t] = mfma16(pa1, vb[ks][t], acco[1][t]);
      }
    }
    __builtin_amdgcn_s_setprio(0);
  };

  bf16x8 kfA[4][2], kfB[4][2];
  loadK(kfA, 0);
  for (int kb = 0; kb < Nn; kb += 128) {
    int n1 = kb + 64;
    int n2 = (kb + 128 < Nn) ? (kb + 128) : 0;
    process(kfA, kb, kfB, n1);
    process(kfB, n1, kfA, n2);
  }

  // epilogue: reduce l across the 16-lane group, divide, write bf16 O (swz)
  #pragma unroll
  for (int qi = 0; qi < 2; qi++)
  #pragma unroll
  for (int r = 0; r < 4; r++) {
    float lsum = l_run[qi][r];
    #pragma unroll
    for (int off = 1; off < 16; off <<= 1) lsum += __shfl_xor(lsum, off);
    l_run[qi][r] = lsum;
  }
  #pragma unroll
  for (int qi = 0; qi < 2; qi++)
  #pragma unroll
  for (int t = 0; t < 4; t++)
  #pragma unroll
  for (int r = 0; r < 4; r++) {
    int q = b * Nn + q0 + qi * 16 + lg * 4 + r;
    Obf[swz(q, h * 64 + t * 16 + lr, Dd)] = f2bf(acco[qi][t][r] / l_run[qi][r]);
  }
}

// ---------------------------------------------------------------------------
extern "C" void kernel_launch(void* const* d_in, const int* in_sizes, int n_in,
                              void* d_out, int out_size, void* d_ws, size_t ws_size,
                              hipStream_t stream) {
  const float* X    = (const float*)d_in[0];
  const int*   train= (const int*)d_in[1];
  const int*   batch= (const int*)d_in[2];
  const float* Wq   = (const float*)d_in[3];
  const float* bq   = (const float*)d_in[4];
  const float* Wk   = (const float*)d_in[5];
  const float* bk   = (const float*)d_in[6];
  const float* Wv   = (const float*)d_in[7];
  const float* bv   = (const float*)d_in[8];
  const float* Wmix = (const float*)d_in[9];
  const float* bmix = (const float*)d_in[10];
  const float* ln0s = (const float*)d_in[11];
  const float* ln0b = (const float*)d_in[12];
  const float* ln1s = (const float*)d_in[13];
  const float* ln1b = (const float*)d_in[14];
  const float* wi0  = (const float*)d_in[15];
  const float* wi1  = (const float*)d_in[16];
  const float* wo   = (const float*)d_in[17];
  float* out = (float*)d_out;

  char* ws = (char*)d_ws;
  size_t off = 0;
  auto alloc = [&](size_t bytes) {
    off = (off + 255) & ~(size_t)255;
    void* p = ws + off; off += bytes; return p;
  };
  short* Xbf   = (short*)alloc((size_t)Mrows * Dd * 2);
  short* Xnbf  = (short*)alloc((size_t)Mrows * Dd * 2);
  short* Qbf   = (short*)alloc((size_t)Mrows * Dd * 2);
  short* Kbf   = (short*)alloc((size_t)Mrows * Dd * 2);
  short* VTg   = (short*)alloc((size_t)Dd * Mrows * 2);   // V^T swz [Dd][Mrows]
  short* Obf   = (short*)alloc((size_t)Mrows * Dd * 2);
  short* x1bf  = (short*)alloc((size_t)Mrows * Dd * 2);
  short* FFbf  = (short*)alloc((size_t)Mrows * FFd * 2);
  short* Hcbf  = (short*)alloc((size_t)Mrows * Dd * 2);   // Hc bf16 swz
  short* WqT   = (short*)alloc((size_t)Dd * Dd * 2);
  short* WkT   = (short*)alloc((size_t)Dd * Dd * 2);
  short* WvT   = (short*)alloc((size_t)Dd * Dd * 2);
  short* WmixT = (short*)alloc((size_t)Dd * Dd * 2);
  short* wi0T  = (short*)alloc((size_t)FFd * Dd * 2);
  short* wi1T  = (short*)alloc((size_t)FFd * Dd * 2);
  short* woT   = (short*)alloc((size_t)Dd * FFd * 2);
  char*  allowC= (char*)alloc((size_t)Mrows);

  dim3 blk(256);
  // transposes + mask + LN0 in one dispatch (6176 blocks)
  PreArgs pa;
  pa.src[0] = Wq;   pa.dst[0] = WqT;
  pa.src[1] = Wk;   pa.dst[1] = WkT;
  pa.src[2] = Wv;   pa.dst[2] = WvT;
  pa.src[3] = Wmix; pa.dst[3] = WmixT;
  pa.src[4] = wi0;  pa.dst[4] = wi0T;
  pa.src[5] = wi1;  pa.dst[5] = wi1T;
  pa.src[6] = wo;   pa.dst[6] = woT;
  pa.train = train; pa.batch = batch; pa.allowC = allowC;
  pa.X = X; pa.sc = ln0s; pa.bi = ln0b; pa.xn = Xnbf; pa.xraw = Xbf;
  k_preprocess<<<6176, blk, 0, stream>>>(pa);

  // Q, K, V^T in one dispatch (1536 blocks, BK=32 -> 6 blocks/CU resident)
  k_qkv<<<1536, blk, 0, stream>>>(Xnbf, Xbf, WqT, WkT, WvT, bq, bk, bv,
                                  Qbf, Kbf, VTg);

  // attention (128 q-rows per block, grid 512, XCD-pinned per head)
  k_attention<<<Bb * Hh * (Nn / 128), blk, 0, stream>>>(Qbf, Kbf, VTg, allowC, Obf);

  // Hc = O @ Wmix + bmix + Q -> bf16 swz (residual from bf16 Qbf)
  k_gemm128<64, 64, 1, 2, false, true><<<dim3(Dd / 64, Mrows / 128), blk, 0, stream>>>(
      Obf, WmixT, bmix, nullptr, Qbf, nullptr, Hcbf, Mrows, Dd, Dd);

  // LN1 (reads bf16 swz Hc)
  k_layernorm1<<<Mrows / 4, blk, 0, stream>>>(Hcbf, ln1s, ln1b, x1bf);

  // FF = gelu(x1@wi0) * (x1@wi1), fused dual-acc BN=64 (2048 blocks)
  k_geglu64<<<2048, blk, 0, stream>>>(x1bf, wi0T, wi1T, FFbf);

  // out = Hc + FF @ wo  -- BK=64, residual from bf16 Hcbf
  k_gemm128<64, 64, 0, 2, true, false><<<dim3(Dd / 64, Mrows / 128), blk, 0, stream>>>(
      FFbf, woT, nullptr, nullptr, Hcbf, out, nullptr, Mrows, Dd, FFd);
}